// Round 5
// baseline (231.437 us; speedup 1.0000x reference)
//
#include <hip/hip_runtime.h>

#define Bn 512
#define Kn 160
#define Hn 256
#define BK (Bn*Kn)
#define ALPHA 0.5f
#define MAX_SPAN 30
#define L_FGW 0.1f
#define L_SPAN 0.5f
#define L_CONS 0.3f
#define KP 16
#define NP 10
#define RCH 40

typedef __bf16 bf16x8 __attribute__((ext_vector_type(8)));
typedef float f32x16 __attribute__((ext_vector_type(16)));

// raw barrier: LDS drained, global loads stay in flight (no vmcnt drain)
__device__ __forceinline__ void wg_barrier() {
  asm volatile("s_waitcnt lgkmcnt(0)" ::: "memory");
  __builtin_amdgcn_s_barrier();
  __builtin_amdgcn_sched_barrier(0);
}

// ---- QA head logits: one wave per (emb,row); H=256 = 64 lanes x float4 ----
__global__ __launch_bounds__(256) void qa_logits_k(
    const float* __restrict__ en, const float* __restrict__ vi,
    const float* __restrict__ w_s, const float* __restrict__ b_s,
    const float* __restrict__ w_e, const float* __restrict__ b_e,
    float* __restrict__ wsl, float* __restrict__ acc) {
  if (blockIdx.x == 0 && threadIdx.x < 16) acc[threadIdx.x] = 0.f;
  int row = blockIdx.x * 4 + (threadIdx.x >> 6);
  int lane = threadIdx.x & 63;
  bool isVi = row >= BK;
  int r = isVi ? row - BK : row;
  const float* emb = isVi ? vi : en;
  float4 v = *(const float4*)(emb + (size_t)r * Hn + lane * 4);
  float4 a = *(const float4*)(w_s + lane * 4);
  float4 c = *(const float4*)(w_e + lane * 4);
  float ds = v.x*a.x + v.y*a.y + v.z*a.z + v.w*a.w;
  float de = v.x*c.x + v.y*c.y + v.z*c.z + v.w*c.w;
  #pragma unroll
  for (int o = 32; o; o >>= 1) { ds += __shfl_xor(ds, o); de += __shfl_xor(de, o); }
  if (lane == 0) {
    size_t base = isVi ? (size_t)2 * BK : 0;
    wsl[base + r] = ds + b_s[0];
    wsl[base + BK + r] = de + b_e[0];
  }
}

// ---- streaming gamma/M pass: p (direct), q & vi_score (global atomics), w ----
// 4 blocks per batch (40-row chunks), 320 threads: thread = (colgroup g, rowmod rr).
__global__ __launch_bounds__(320) void stats_part_k(
    const float* __restrict__ gam, const float* __restrict__ M,
    const int* __restrict__ enst, const int* __restrict__ enen,
    float* __restrict__ p_arr, float* __restrict__ q_arr,
    float* __restrict__ vsc_arr, float* __restrict__ acc) {
  __shared__ float psh[RCH];
  __shared__ float qsh[Kn];
  __shared__ float vsh[Kn];
  __shared__ float wsh[5];
  int bid = blockIdx.x;
  int b = bid >> 2;
  int ch = bid & 3;
  int r0 = ch * RCH;
  int tid = threadIdx.x;
  int g = tid % 40;
  int rr = tid / 40;
  for (int t = tid; t < RCH; t += 320) psh[t] = 0.f;
  for (int t = tid; t < Kn; t += 320) { qsh[t] = 0.f; vsh[t] = 0.f; }
  __syncthreads();
  int s0 = enst[b], e0 = enen[b];
  int s = min(max(s0, 0), Kn - 1);
  int e = max(s, min(max(e0, 0), Kn - 1));
  const float* gb = gam + (size_t)b * Kn * Kn + (size_t)r0 * Kn;
  const float* mb = M + (size_t)b * Kn * Kn + (size_t)r0 * Kn;
  float q4[4] = {0.f, 0.f, 0.f, 0.f};
  float v4[4] = {0.f, 0.f, 0.f, 0.f};
  float wloc = 0.f;
  #pragma unroll
  for (int t = 0; t < 5; ++t) {
    int r = rr + 8 * t;
    float4 gv = *(const float4*)(gb + (size_t)r * Kn + 4 * g);
    float4 mv = *(const float4*)(mb + (size_t)r * Kn + 4 * g);
    wloc += mv.x * gv.x + mv.y * gv.y + mv.z * gv.z + mv.w * gv.w;
    atomicAdd(&psh[r], gv.x + gv.y + gv.z + gv.w);
    q4[0] += gv.x; q4[1] += gv.y; q4[2] += gv.z; q4[3] += gv.w;
    int ra = r0 + r;
    float f = (ra >= s && ra <= e) ? 1.f : 0.f;
    v4[0] += f * gv.x; v4[1] += f * gv.y; v4[2] += f * gv.z; v4[3] += f * gv.w;
  }
  #pragma unroll
  for (int j = 0; j < 4; ++j) {
    atomicAdd(&qsh[4 * g + j], q4[j]);
    atomicAdd(&vsh[4 * g + j], v4[j]);
  }
  #pragma unroll
  for (int o = 32; o; o >>= 1) wloc += __shfl_xor(wloc, o);
  int wid = tid >> 6, lane = tid & 63;
  if (lane == 0) wsh[wid] = wloc;
  __syncthreads();
  if (tid < RCH) p_arr[(size_t)b * Kn + r0 + tid] = psh[tid];
  if (tid < Kn) {
    atomicAdd(&q_arr[(size_t)b * Kn + tid], qsh[tid]);
    atomicAdd(&vsc_arr[(size_t)b * Kn + tid], vsh[tid]);
  }
  if (tid == 0) atomicAdd(acc + 4, wsh[0] + wsh[1] + wsh[2] + wsh[3] + wsh[4]);
}

// ---- span decode + QA CE + consistency KL + span CE; one block per batch ----
__global__ __launch_bounds__(256) void stats_reduce_k(
    const float* __restrict__ vsc_arr, const int* __restrict__ enst,
    const int* __restrict__ enen, const float* __restrict__ wsl,
    float* __restrict__ acc) {
  __shared__ float vsc[Kn];
  __shared__ float bv[256];
  __shared__ int bidx[256];
  __shared__ int pspe[2];
  int b = blockIdx.x, tid = threadIdx.x;
  int wid = tid >> 6, lane = tid & 63;
  int s0 = enst[b], e0 = enen[b];
  if (tid < Kn) vsc[tid] = vsc_arr[(size_t)b * Kn + tid];
  __syncthreads();
  float best = -1e30f;
  int bfl = 0x7fffffff;
  if (tid < Kn) {
    float vsi = vsc[tid];
    int hi = min(tid + MAX_SPAN, Kn - 1);
    for (int ei = tid; ei <= hi; ++ei) {
      float v = vsi + vsc[ei];
      if (v > best) { best = v; bfl = tid * Kn + ei; }  // first-max (np.argmax)
    }
  }
  bv[tid] = best; bidx[tid] = bfl;
  for (int st = 128; st > 0; st >>= 1) {
    __syncthreads();
    if (tid < st) {
      float v2 = bv[tid + st]; int i2 = bidx[tid + st];
      if (v2 > bv[tid] || (v2 == bv[tid] && i2 < bidx[tid])) { bv[tid] = v2; bidx[tid] = i2; }
    }
  }
  if (tid == 0) {
    int fl = bidx[0];
    int ps = fl / Kn, pe = fl - (fl / Kn) * Kn;
    if (s0 == 0 && e0 == 0) { ps = 0; pe = 0; }
    pspe[0] = ps; pspe[1] = pe;
  }
  __syncthreads();
  if (wid == 0) {
    const float* es = wsl + (size_t)b * Kn;
    const float* ee = wsl + (size_t)BK + (size_t)b * Kn;
    const float* vs = wsl + (size_t)2 * BK + (size_t)b * Kn;
    const float* ve = wsl + (size_t)3 * BK + (size_t)b * Kn;
    float xes[3], xee[3], xvs[3], xve[3];
    #pragma unroll
    for (int j = 0; j < 3; ++j) {
      int idx = lane + 64 * j;
      bool val = idx < Kn;
      xes[j] = val ? es[idx] : -1e30f;
      xee[j] = val ? ee[idx] : -1e30f;
      xvs[j] = val ? vs[idx] : -1e30f;
      xve[j] = val ? ve[idx] : -1e30f;
    }
    auto wlse = [&](float x0, float x1, float x2) -> float {
      float m = fmaxf(fmaxf(x0, x1), x2);
      #pragma unroll
      for (int o = 32; o; o >>= 1) m = fmaxf(m, __shfl_xor(m, o));
      float su = expf(x0 - m) + expf(x1 - m) + expf(x2 - m);
      #pragma unroll
      for (int o = 32; o; o >>= 1) su += __shfl_xor(su, o);
      return m + logf(su);
    };
    float l_es = wlse(xes[0], xes[1], xes[2]);
    float l_ee = wlse(xee[0], xee[1], xee[2]);
    float l_vs = wlse(xvs[0], xvs[1], xvs[2]);
    float l_ve = wlse(xve[0], xve[1], xve[2]);
    float lT_es = wlse(xes[0]*0.5f, xes[1]*0.5f, xes[2]*0.5f);
    float lT_ee = wlse(xee[0]*0.5f, xee[1]*0.5f, xee[2]*0.5f);
    float lT_vs = wlse(xvs[0]*0.5f, xvs[1]*0.5f, xvs[2]*0.5f);
    float lT_ve = wlse(xve[0]*0.5f, xve[1]*0.5f, xve[2]*0.5f);
    float kls = 0.f, kle = 0.f;
    #pragma unroll
    for (int j = 0; j < 3; ++j) {
      int idx = lane + 64 * j;
      if (idx < Kn) {
        float aa = xes[j]*0.5f - lT_es;
        float bb = xvs[j]*0.5f - lT_vs;
        kls += expf(aa) * (aa - bb);
        float cc = xee[j]*0.5f - lT_ee;
        float dd = xve[j]*0.5f - lT_ve;
        kle += expf(cc) * (cc - dd);
      }
    }
    #pragma unroll
    for (int o = 32; o; o >>= 1) { kls += __shfl_xor(kls, o); kle += __shfl_xor(kle, o); }
    if (lane == 0) {
      int sl = min(max(s0, 0), Kn - 1);
      int el = min(max(e0, 0), Kn - 1);
      atomicAdd(acc + 0, l_es - es[sl]);
      atomicAdd(acc + 1, l_ee - ee[el]);
      atomicAdd(acc + 2, kls);
      atomicAdd(acc + 3, kle);
      if (s0 > 0 || e0 > 0) {
        float ce = 0.5f * ((l_vs - vs[pspe[0]]) + (l_ve - ve[pspe[1]]));
        atomicAdd(acc + 8, ce);
        atomicAdd(acc + 9, 1.f);
      }
    }
  }
}

// ---- MFMA FGW, software-pipelined: loads for panel p+2 issued in phase p,
// ds_write in phase p+1, raw s_barrier (lgkm-only drain) so global loads
// stay in flight across barriers. 2 blocks/batch (column halves).
__global__ __launch_bounds__(512, 3) void fgw_k(
    const float* __restrict__ Den, const float* __restrict__ Dvi,
    const float* __restrict__ gam, const float* __restrict__ p_arr,
    const float* __restrict__ q_arr, float* __restrict__ acc) {
  __shared__ __align__(16) __bf16 sDen[2][2][Kn][8];
  __shared__ __align__(16) __bf16 sG  [2][2][Kn][8];
  __shared__ __align__(16) __bf16 sGT [2][2][96][8];
  __shared__ __align__(16) __bf16 sVT [2][2][96][8];
  __shared__ float pq[2 * Kn];
  __shared__ float red[24];
  int bid = blockIdx.x;
  int h = (bid >> 3) & 1;
  int b = ((bid >> 4) << 3) | (bid & 7);
  const int JB = h ? 96 : 0;
  const int NBJ = h ? 64 : 96;
  const int NTJ = h ? 2 : 3;
  const int NT = 5 * NTJ;
  int tid = threadIdx.x;
  int wid = tid >> 6, lane = tid & 63;
  const float* den_b = Den + (size_t)b * Kn * Kn;
  const float* dvi_b = Dvi + (size_t)b * Kn * Kn;
  const float* gam_b = gam + (size_t)b * Kn * Kn;
  if (tid < 2 * Kn)
    pq[tid] = (tid < Kn) ? p_arr[(size_t)b * Kn + tid]
                         : q_arr[(size_t)b * Kn + (tid - Kn)];
  __syncthreads();

  // slot0 (tau=tid, 0..511): always row-major. tau<320 -> sDen, else sG.
  int op0 = tid >= 320 ? 1 : 0;
  int f0 = tid - 320 * op0;
  int c0 = f0 >= Kn ? 1 : 0;
  int r0 = f0 - Kn * c0;
  const float* s0p = (op0 ? gam_b : den_b) + (size_t)r0 * Kn + 8 * c0;
  __bf16* d00 = op0 ? &sG[0][c0][r0][0] : &sDen[0][c0][r0][0];
  __bf16* d01 = op0 ? &sG[1][c0][r0][0] : &sDen[1][c0][r0][0];
  int gw1k = (!op0 && h == 0) ? 1 : 0;
  float wgt0 = gw1k ? pq[r0] : 0.f;
  const float* pqb0 = pq + 8 * c0;
  // slot1 (tau=tid+512): tid<128 -> row-major (sG,c=1,r=tid+32); else transposed.
  bool rm1 = tid < 128;
  bool act1 = (tid + 512) < (640 + 4 * NBJ);
  const float* s1p = den_b;
  __bf16* d10 = &sGT[0][0][0][0];
  __bf16* d11 = &sGT[1][0][0][0];
  int gw2k = 0;
  float wgt1 = 0.f;
  const float* pqb1 = pq;
  if (act1) {
    if (rm1) {
      int r1 = tid + 32;
      s1p = gam_b + (size_t)r1 * Kn + 8;
      d10 = &sG[0][1][r1][0];
      d11 = &sG[1][1][r1][0];
    } else {
      int f2 = tid - 128;
      int op1 = f2 >= 2 * NBJ ? 1 : 0;
      int f = f2 - 2 * NBJ * op1;
      int c1 = f >= NBJ ? 1 : 0;
      int r1 = f - NBJ * c1;
      int j = JB + r1;
      s1p = (op1 ? dvi_b : gam_b) + (size_t)(8 * c1) * Kn + j;
      d10 = op1 ? &sVT[0][c1][r1][0] : &sGT[0][c1][r1][0];
      d11 = op1 ? &sVT[1][c1][r1][0] : &sGT[1][c1][r1][0];
      if (op1) { gw2k = 1; wgt1 = pq[Kn + j]; pqb1 = pq + Kn + 8 * c1; }
    }
  }
  float gw1a = 0.f, gw2a = 0.f;
  float vA0[8], vA1[8], vB0[8], vB1[8];

  auto load0 = [&](int p, float* v) {
    const float* sp = s0p + p * KP;
    float4 x = *(const float4*)sp;
    float4 y = *(const float4*)(sp + 4);
    v[0]=x.x; v[1]=x.y; v[2]=x.z; v[3]=x.w;
    v[4]=y.x; v[5]=y.y; v[6]=y.z; v[7]=y.w;
  };
  auto load1 = [&](int p, float* v) {
    if (!act1) return;
    if (rm1) {
      const float* sp = s1p + p * KP;
      float4 x = *(const float4*)sp;
      float4 y = *(const float4*)(sp + 4);
      v[0]=x.x; v[1]=x.y; v[2]=x.z; v[3]=x.w;
      v[4]=y.x; v[5]=y.y; v[6]=y.z; v[7]=y.w;
    } else {
      const float* sp = s1p + (size_t)p * KP * Kn;
      #pragma unroll
      for (int e2 = 0; e2 < 8; ++e2) v[e2] = sp[(size_t)e2 * Kn];
    }
  };
  auto wr = [&](int p, const float* v0, const float* v1, __bf16* w0, __bf16* w1) {
    if (gw1k) {
      const float* pp = pqb0 + p * KP;
      float g = 0.f;
      #pragma unroll
      for (int e2 = 0; e2 < 8; ++e2) g += v0[e2] * v0[e2] * pp[e2];
      gw1a += g * wgt0;
    }
    bf16x8 wv;
    #pragma unroll
    for (int e2 = 0; e2 < 8; ++e2) wv[e2] = (__bf16)v0[e2];
    *(bf16x8*)w0 = wv;
    if (act1) {
      if (gw2k) {
        const float* pp = pqb1 + p * KP;
        float g = 0.f;
        #pragma unroll
        for (int e2 = 0; e2 < 8; ++e2) g += v1[e2] * v1[e2] * pp[e2];
        gw2a += g * wgt1;
      }
      bf16x8 wv2;
      #pragma unroll
      for (int e2 = 0; e2 < 8; ++e2) wv2[e2] = (__bf16)v1[e2];
      *(bf16x8*)w1 = wv2;
    }
  };

  int ra = lane & 31, cc2 = lane >> 5;
  int t1i = wid + 8;
  bool val1t = t1i < NT;
  int ti0 = wid / NTJ, tj0 = wid - ti0 * NTJ;
  int rowa0 = ti0 * 32 + ra, rowb0 = tj0 * 32 + ra;
  int ti1 = t1i / NTJ, tj1 = t1i - ti1 * NTJ;
  int rowa1 = ti1 * 32 + ra, rowb1 = tj1 * 32 + ra;
  f32x16 acc10 = {}, acc20 = {}, acc11 = {}, acc21 = {};
  auto mf = [&](int BUF) {
    {
      bf16x8 a1 = *(const bf16x8*)&sDen[BUF][cc2][rowa0][0];
      bf16x8 b1 = *(const bf16x8*)&sGT[BUF][cc2][rowb0][0];
      bf16x8 a2 = *(const bf16x8*)&sG[BUF][cc2][rowa0][0];
      bf16x8 b2 = *(const bf16x8*)&sVT[BUF][cc2][rowb0][0];
      acc10 = __builtin_amdgcn_mfma_f32_32x32x16_bf16(a1, b1, acc10, 0, 0, 0);
      acc20 = __builtin_amdgcn_mfma_f32_32x32x16_bf16(a2, b2, acc20, 0, 0, 0);
    }
    if (val1t) {
      bf16x8 a1 = *(const bf16x8*)&sDen[BUF][cc2][rowa1][0];
      bf16x8 b1 = *(const bf16x8*)&sGT[BUF][cc2][rowb1][0];
      bf16x8 a2 = *(const bf16x8*)&sG[BUF][cc2][rowa1][0];
      bf16x8 b2 = *(const bf16x8*)&sVT[BUF][cc2][rowb1][0];
      acc11 = __builtin_amdgcn_mfma_f32_32x32x16_bf16(a1, b1, acc11, 0, 0, 0);
      acc21 = __builtin_amdgcn_mfma_f32_32x32x16_bf16(a2, b2, acc21, 0, 0, 0);
    }
  };

  load0(0, vA0); load1(0, vA1);
  load0(1, vB0); load1(1, vB1);
  wr(0, vA0, vA1, d00, d10);
  __syncthreads();
  for (int p = 0; p < NP; p += 2) {
    if (p + 2 < NP) { load0(p + 2, vA0); load1(p + 2, vA1); }
    mf(0);
    wr(p + 1, vB0, vB1, d01, d11);
    wg_barrier();
    if (p + 3 < NP) { load0(p + 3, vB0); load1(p + 3, vB1); }
    mf(1);
    if (p + 2 < NP) wr(p + 2, vA0, vA1, d00, d10);
    wg_barrier();
  }
  float g3 = 0.f;
  #pragma unroll
  for (int r2 = 0; r2 < 16; ++r2) g3 += acc10[r2] * acc20[r2];
  if (val1t) {
    #pragma unroll
    for (int r2 = 0; r2 < 16; ++r2) g3 += acc11[r2] * acc21[r2];
  }
  #pragma unroll
  for (int o = 32; o; o >>= 1) {
    gw1a += __shfl_xor(gw1a, o);
    gw2a += __shfl_xor(gw2a, o);
    g3 += __shfl_xor(g3, o);
  }
  if (lane == 0) { red[wid] = gw1a; red[8 + wid] = gw2a; red[16 + wid] = g3; }
  __syncthreads();
  if (tid == 0) {
    float s1 = 0.f, s2 = 0.f, s3 = 0.f;
    #pragma unroll
    for (int i = 0; i < 8; ++i) { s1 += red[i]; s2 += red[8 + i]; s3 += red[16 + i]; }
    if (h == 0) atomicAdd(acc + 5, s1);
    atomicAdd(acc + 6, s2);
    atomicAdd(acc + 7, s3);
  }
}

__global__ void finalize_k(const float* __restrict__ acc, float* __restrict__ out) {
  if (threadIdx.x == 0) {
    float ce_s = acc[0], ce_e = acc[1], kls = acc[2], kle = acc[3];
    float w = acc[4], gw1 = acc[5], gw2 = acc[6], gw3 = acc[7];
    float spn = acc[8], nans = acc[9];
    float l_qa = (ce_s + ce_e) / (2.f * Bn);
    float l_fgw = (ALPHA * (gw1 + gw2 - 2.f * gw3) + (1.f - ALPHA) * w) / Bn;
    float l_span = (nans > 0.f) ? spn / fmaxf(nans, 1.f) : 0.f;
    float l_cons = 2.f * (kls + kle) / Bn;  // T^2 * ((kls+kle)/B) / 2 with T=2
    float total = l_qa + L_FGW * l_fgw + L_SPAN * l_span + L_CONS * l_cons;
    out[0] = total; out[1] = l_qa; out[2] = l_fgw; out[3] = l_span; out[4] = l_cons;
  }
}

extern "C" void kernel_launch(void* const* d_in, const int* in_sizes, int n_in,
                              void* d_out, int out_size, void* d_ws, size_t ws_size,
                              hipStream_t stream) {
  const float* en  = (const float*)d_in[0];
  const float* vi  = (const float*)d_in[1];
  const float* gam = (const float*)d_in[2];
  const float* Den = (const float*)d_in[3];
  const float* Dvi = (const float*)d_in[4];
  const float* M   = (const float*)d_in[5];
  const int* enst  = (const int*)d_in[6];
  const int* enen  = (const int*)d_in[7];
  const float* w_s = (const float*)d_in[8];
  const float* b_s = (const float*)d_in[9];
  const float* w_e = (const float*)d_in[10];
  const float* b_e = (const float*)d_in[11];
  float* ws = (float*)d_ws;
  float* wsl = ws;                         // 4*BK logits
  float* p_arr = ws + (size_t)4 * BK;      // BK
  float* q_arr = p_arr + BK;               // BK
  float* vsc_arr = q_arr + BK;             // BK
  float* acc = vsc_arr + BK;               // 16 accumulators
  float* out = (float*)d_out;

  // zero the atomically-accumulated buffers (q, vsc) once per call
  hipMemsetAsync(q_arr, 0, (size_t)2 * BK * sizeof(float), stream);
  qa_logits_k<<<(2 * BK) / 4, 256, 0, stream>>>(en, vi, w_s, b_s, w_e, b_e, wsl, acc);
  stats_part_k<<<4 * Bn, 320, 0, stream>>>(gam, M, enst, enen, p_arr, q_arr, vsc_arr, acc);
  stats_reduce_k<<<Bn, 256, 0, stream>>>(vsc_arr, enst, enen, wsl, acc);
  fgw_k<<<2 * Bn, 512, 0, stream>>>(Den, Dvi, gam, p_arr, q_arr, acc);
  finalize_k<<<1, 64, 0, stream>>>(acc, out);
}

// Round 6
// 188.876 us; speedup vs baseline: 1.2253x; 1.2253x over previous
//
#include <hip/hip_runtime.h>

#define Bn 512
#define Kn 160
#define Hn 256
#define BK (Bn*Kn)
#define ALPHA 0.5f
#define MAX_SPAN 30
#define L_FGW 0.1f
#define L_SPAN 0.5f
#define L_CONS 0.3f
#define KP 16
#define NP 10

typedef __bf16 bf16x8 __attribute__((ext_vector_type(8)));
typedef float f32x16 __attribute__((ext_vector_type(16)));

// raw barrier: LDS drained, global loads stay in flight (no vmcnt drain)
__device__ __forceinline__ void wg_barrier() {
  asm volatile("s_waitcnt lgkmcnt(0)" ::: "memory");
  __builtin_amdgcn_s_barrier();
  __builtin_amdgcn_sched_barrier(0);
}

// ---- QA head logits: one wave per (emb,row); H=256 = 64 lanes x float4 ----
__global__ __launch_bounds__(256) void qa_logits_k(
    const float* __restrict__ en, const float* __restrict__ vi,
    const float* __restrict__ w_s, const float* __restrict__ b_s,
    const float* __restrict__ w_e, const float* __restrict__ b_e,
    float* __restrict__ wsl, float* __restrict__ acc) {
  if (blockIdx.x == 0 && threadIdx.x < 16) acc[threadIdx.x] = 0.f;
  int row = blockIdx.x * 4 + (threadIdx.x >> 6);
  int lane = threadIdx.x & 63;
  bool isVi = row >= BK;
  int r = isVi ? row - BK : row;
  const float* emb = isVi ? vi : en;
  float4 v = *(const float4*)(emb + (size_t)r * Hn + lane * 4);
  float4 a = *(const float4*)(w_s + lane * 4);
  float4 c = *(const float4*)(w_e + lane * 4);
  float ds = v.x*a.x + v.y*a.y + v.z*a.z + v.w*a.w;
  float de = v.x*c.x + v.y*c.y + v.z*c.z + v.w*c.w;
  #pragma unroll
  for (int o = 32; o; o >>= 1) { ds += __shfl_xor(ds, o); de += __shfl_xor(de, o); }
  if (lane == 0) {
    size_t base = isVi ? (size_t)2 * BK : 0;
    wsl[base + r] = ds + b_s[0];
    wsl[base + BK + r] = de + b_e[0];
  }
}

// ---- fused: gamma stats (p,q,w) + span decode + QA CE + KL + span CE ----
// Hot loop is PURE load+FMA: per-row sums buffered in 20 registers per lane,
// all cross-lane reductions deferred to the end (off the load critical path).
__global__ __launch_bounds__(512) void stats_logit_k(
    const float* __restrict__ gam, const float* __restrict__ M,
    const int* __restrict__ enst, const int* __restrict__ enen,
    const float* __restrict__ wsl, float* __restrict__ p_arr,
    float* __restrict__ q_arr, float* __restrict__ acc) {
  __shared__ float qsh[Kn];
  __shared__ float vsc[Kn];
  __shared__ float wsh[8];
  __shared__ float bv[512];
  __shared__ int bidx[512];
  __shared__ int pspe[2];
  int b = blockIdx.x, tid = threadIdx.x;
  int wid = tid >> 6, lane = tid & 63;
  for (int t = tid; t < Kn; t += 512) { qsh[t] = 0.f; vsc[t] = 0.f; }
  __syncthreads();
  int s0 = enst[b], e0 = enen[b];
  int s = min(max(s0, 0), Kn - 1);
  int e = max(s, min(max(e0, 0), Kn - 1));
  const float* gb = gam + (size_t)b * Kn * Kn;
  const float* mb = M + (size_t)b * Kn * Kn;
  bool tail = lane < 16;
  float qx = 0.f, qy = 0.f, qz = 0.f, qw = 0.f;
  float vx = 0.f, vy = 0.f, vz = 0.f, vw = 0.f;
  float wloc = 0.f;
  float p20[20];
  #pragma unroll 4
  for (int it = 0; it < 20; ++it) {
    int i = wid + 8 * it;
    const float2* g2 = (const float2*)(gb + (size_t)i * Kn);
    const float2* m2 = (const float2*)(mb + (size_t)i * Kn);
    float2 gA = g2[lane];
    float2 mA = m2[lane];
    float2 gB = {0.f, 0.f}, mB = {0.f, 0.f};
    if (tail) { gB = g2[64 + lane]; mB = m2[64 + lane]; }
    qx += gA.x; qy += gA.y; qz += gB.x; qw += gB.y;
    wloc += mA.x * gA.x + mA.y * gA.y + mB.x * gB.x + mB.y * gB.y;
    p20[it] = gA.x + gA.y + gB.x + gB.y;   // per-lane partial, reduced later
    float f = (i >= s && i <= e) ? 1.f : 0.f;
    vx += f * gA.x; vy += f * gA.y; vz += f * gB.x; vw += f * gB.y;
  }
  // ---- deferred reductions ----
  #pragma unroll
  for (int it = 0; it < 20; ++it) {
    float rs = p20[it];
    #pragma unroll
    for (int o = 32; o; o >>= 1) rs += __shfl_xor(rs, o);
    if (lane == 0) p_arr[(size_t)b * Kn + wid + 8 * it] = rs;
  }
  atomicAdd(&qsh[2 * lane], qx); atomicAdd(&qsh[2 * lane + 1], qy);
  atomicAdd(&vsc[2 * lane], vx); atomicAdd(&vsc[2 * lane + 1], vy);
  if (tail) {
    atomicAdd(&qsh[128 + 2 * lane], qz); atomicAdd(&qsh[128 + 2 * lane + 1], qw);
    atomicAdd(&vsc[128 + 2 * lane], vz); atomicAdd(&vsc[128 + 2 * lane + 1], vw);
  }
  #pragma unroll
  for (int o = 32; o; o >>= 1) wloc += __shfl_xor(wloc, o);
  if (lane == 0) wsh[wid] = wloc;
  __syncthreads();
  if (tid < Kn) q_arr[(size_t)b * Kn + tid] = qsh[tid];
  if (tid == 0) {
    float sw = 0.f;
    #pragma unroll
    for (int i2 = 0; i2 < 8; ++i2) sw += wsh[i2];
    atomicAdd(acc + 4, sw);
  }
  // ---- span argmax (first-max semantics) ----
  float best = -1e30f;
  int bfl = 0x7fffffff;
  if (tid < Kn) {
    float vsi = vsc[tid];
    int hi = min(tid + MAX_SPAN, Kn - 1);
    for (int ei = tid; ei <= hi; ++ei) {
      float v = vsi + vsc[ei];
      if (v > best) { best = v; bfl = tid * Kn + ei; }
    }
  }
  bv[tid] = best; bidx[tid] = bfl;
  for (int st = 256; st > 0; st >>= 1) {
    __syncthreads();
    if (tid < st) {
      float v2 = bv[tid + st]; int i2 = bidx[tid + st];
      if (v2 > bv[tid] || (v2 == bv[tid] && i2 < bidx[tid])) { bv[tid] = v2; bidx[tid] = i2; }
    }
  }
  if (tid == 0) {
    int fl = bidx[0];
    int ps = fl / Kn, pe = fl - (fl / Kn) * Kn;
    if (s0 == 0 && e0 == 0) { ps = 0; pe = 0; }
    pspe[0] = ps; pspe[1] = pe;
  }
  __syncthreads();
  // ---- logit losses: wave 0 only ----
  if (wid == 0) {
    const float* es = wsl + (size_t)b * Kn;
    const float* ee = wsl + (size_t)BK + (size_t)b * Kn;
    const float* vs = wsl + (size_t)2 * BK + (size_t)b * Kn;
    const float* ve = wsl + (size_t)3 * BK + (size_t)b * Kn;
    float xes[3], xee[3], xvs[3], xve[3];
    #pragma unroll
    for (int j = 0; j < 3; ++j) {
      int idx = lane + 64 * j;
      bool val = idx < Kn;
      xes[j] = val ? es[idx] : -1e30f;
      xee[j] = val ? ee[idx] : -1e30f;
      xvs[j] = val ? vs[idx] : -1e30f;
      xve[j] = val ? ve[idx] : -1e30f;
    }
    auto wlse = [&](float x0, float x1, float x2) -> float {
      float m = fmaxf(fmaxf(x0, x1), x2);
      #pragma unroll
      for (int o = 32; o; o >>= 1) m = fmaxf(m, __shfl_xor(m, o));
      float su = expf(x0 - m) + expf(x1 - m) + expf(x2 - m);
      #pragma unroll
      for (int o = 32; o; o >>= 1) su += __shfl_xor(su, o);
      return m + logf(su);
    };
    float l_es = wlse(xes[0], xes[1], xes[2]);
    float l_ee = wlse(xee[0], xee[1], xee[2]);
    float l_vs = wlse(xvs[0], xvs[1], xvs[2]);
    float l_ve = wlse(xve[0], xve[1], xve[2]);
    float lT_es = wlse(xes[0]*0.5f, xes[1]*0.5f, xes[2]*0.5f);
    float lT_ee = wlse(xee[0]*0.5f, xee[1]*0.5f, xee[2]*0.5f);
    float lT_vs = wlse(xvs[0]*0.5f, xvs[1]*0.5f, xvs[2]*0.5f);
    float lT_ve = wlse(xve[0]*0.5f, xve[1]*0.5f, xve[2]*0.5f);
    float kls = 0.f, kle = 0.f;
    #pragma unroll
    for (int j = 0; j < 3; ++j) {
      int idx = lane + 64 * j;
      if (idx < Kn) {
        float aa = xes[j]*0.5f - lT_es;
        float bb = xvs[j]*0.5f - lT_vs;
        kls += expf(aa) * (aa - bb);
        float cc = xee[j]*0.5f - lT_ee;
        float dd = xve[j]*0.5f - lT_ve;
        kle += expf(cc) * (cc - dd);
      }
    }
    #pragma unroll
    for (int o = 32; o; o >>= 1) { kls += __shfl_xor(kls, o); kle += __shfl_xor(kle, o); }
    if (lane == 0) {
      int sl = min(max(s0, 0), Kn - 1);
      int el = min(max(e0, 0), Kn - 1);
      atomicAdd(acc + 0, l_es - es[sl]);
      atomicAdd(acc + 1, l_ee - ee[el]);
      atomicAdd(acc + 2, kls);
      atomicAdd(acc + 3, kle);
      if (s0 > 0 || e0 > 0) {
        float ce = 0.5f * ((l_vs - vs[pspe[0]]) + (l_ve - ve[pspe[1]]));
        atomicAdd(acc + 8, ce);
        atomicAdd(acc + 9, 1.f);
      }
    }
  }
}

// ---- MFMA FGW, software-pipelined: loads for panel p+2 issued in phase p,
// ds_write in phase p+1, raw s_barrier (lgkm-only drain) so global loads
// stay in flight across barriers. 2 blocks/batch (column halves).
__global__ __launch_bounds__(512, 3) void fgw_k(
    const float* __restrict__ Den, const float* __restrict__ Dvi,
    const float* __restrict__ gam, const float* __restrict__ p_arr,
    const float* __restrict__ q_arr, float* __restrict__ acc) {
  __shared__ __align__(16) __bf16 sDen[2][2][Kn][8];
  __shared__ __align__(16) __bf16 sG  [2][2][Kn][8];
  __shared__ __align__(16) __bf16 sGT [2][2][96][8];
  __shared__ __align__(16) __bf16 sVT [2][2][96][8];
  __shared__ float pq[2 * Kn];
  __shared__ float red[24];
  int bid = blockIdx.x;
  int h = (bid >> 3) & 1;
  int b = ((bid >> 4) << 3) | (bid & 7);
  const int JB = h ? 96 : 0;
  const int NBJ = h ? 64 : 96;
  const int NTJ = h ? 2 : 3;
  const int NT = 5 * NTJ;
  int tid = threadIdx.x;
  int wid = tid >> 6, lane = tid & 63;
  const float* den_b = Den + (size_t)b * Kn * Kn;
  const float* dvi_b = Dvi + (size_t)b * Kn * Kn;
  const float* gam_b = gam + (size_t)b * Kn * Kn;
  if (tid < 2 * Kn)
    pq[tid] = (tid < Kn) ? p_arr[(size_t)b * Kn + tid]
                         : q_arr[(size_t)b * Kn + (tid - Kn)];
  __syncthreads();

  // slot0 (tau=tid, 0..511): always row-major. tau<320 -> sDen, else sG.
  int op0 = tid >= 320 ? 1 : 0;
  int f0 = tid - 320 * op0;
  int c0 = f0 >= Kn ? 1 : 0;
  int r0 = f0 - Kn * c0;
  const float* s0p = (op0 ? gam_b : den_b) + (size_t)r0 * Kn + 8 * c0;
  __bf16* d00 = op0 ? &sG[0][c0][r0][0] : &sDen[0][c0][r0][0];
  __bf16* d01 = op0 ? &sG[1][c0][r0][0] : &sDen[1][c0][r0][0];
  int gw1k = (!op0 && h == 0) ? 1 : 0;
  float wgt0 = gw1k ? pq[r0] : 0.f;
  const float* pqb0 = pq + 8 * c0;
  // slot1 (tau=tid+512): tid<128 -> row-major (sG,c=1,r=tid+32); else transposed.
  bool rm1 = tid < 128;
  bool act1 = (tid + 512) < (640 + 4 * NBJ);
  const float* s1p = den_b;
  __bf16* d10 = &sGT[0][0][0][0];
  __bf16* d11 = &sGT[1][0][0][0];
  int gw2k = 0;
  float wgt1 = 0.f;
  const float* pqb1 = pq;
  if (act1) {
    if (rm1) {
      int r1 = tid + 32;
      s1p = gam_b + (size_t)r1 * Kn + 8;
      d10 = &sG[0][1][r1][0];
      d11 = &sG[1][1][r1][0];
    } else {
      int f2 = tid - 128;
      int op1 = f2 >= 2 * NBJ ? 1 : 0;
      int f = f2 - 2 * NBJ * op1;
      int c1 = f >= NBJ ? 1 : 0;
      int r1 = f - NBJ * c1;
      int j = JB + r1;
      s1p = (op1 ? dvi_b : gam_b) + (size_t)(8 * c1) * Kn + j;
      d10 = op1 ? &sVT[0][c1][r1][0] : &sGT[0][c1][r1][0];
      d11 = op1 ? &sVT[1][c1][r1][0] : &sGT[1][c1][r1][0];
      if (op1) { gw2k = 1; wgt1 = pq[Kn + j]; pqb1 = pq + Kn + 8 * c1; }
    }
  }
  float gw1a = 0.f, gw2a = 0.f;
  float vA0[8], vA1[8], vB0[8], vB1[8];

  auto load0 = [&](int p, float* v) {
    const float* sp = s0p + p * KP;
    float4 x = *(const float4*)sp;
    float4 y = *(const float4*)(sp + 4);
    v[0]=x.x; v[1]=x.y; v[2]=x.z; v[3]=x.w;
    v[4]=y.x; v[5]=y.y; v[6]=y.z; v[7]=y.w;
  };
  auto load1 = [&](int p, float* v) {
    if (!act1) return;
    if (rm1) {
      const float* sp = s1p + p * KP;
      float4 x = *(const float4*)sp;
      float4 y = *(const float4*)(sp + 4);
      v[0]=x.x; v[1]=x.y; v[2]=x.z; v[3]=x.w;
      v[4]=y.x; v[5]=y.y; v[6]=y.z; v[7]=y.w;
    } else {
      const float* sp = s1p + (size_t)p * KP * Kn;
      #pragma unroll
      for (int e2 = 0; e2 < 8; ++e2) v[e2] = sp[(size_t)e2 * Kn];
    }
  };
  auto wr = [&](int p, const float* v0, const float* v1, __bf16* w0, __bf16* w1) {
    if (gw1k) {
      const float* pp = pqb0 + p * KP;
      float g = 0.f;
      #pragma unroll
      for (int e2 = 0; e2 < 8; ++e2) g += v0[e2] * v0[e2] * pp[e2];
      gw1a += g * wgt0;
    }
    bf16x8 wv;
    #pragma unroll
    for (int e2 = 0; e2 < 8; ++e2) wv[e2] = (__bf16)v0[e2];
    *(bf16x8*)w0 = wv;
    if (act1) {
      if (gw2k) {
        const float* pp = pqb1 + p * KP;
        float g = 0.f;
        #pragma unroll
        for (int e2 = 0; e2 < 8; ++e2) g += v1[e2] * v1[e2] * pp[e2];
        gw2a += g * wgt1;
      }
      bf16x8 wv2;
      #pragma unroll
      for (int e2 = 0; e2 < 8; ++e2) wv2[e2] = (__bf16)v1[e2];
      *(bf16x8*)w1 = wv2;
    }
  };

  int ra = lane & 31, cc2 = lane >> 5;
  int t1i = wid + 8;
  bool val1t = t1i < NT;
  int ti0 = wid / NTJ, tj0 = wid - ti0 * NTJ;
  int rowa0 = ti0 * 32 + ra, rowb0 = tj0 * 32 + ra;
  int ti1 = t1i / NTJ, tj1 = t1i - ti1 * NTJ;
  int rowa1 = ti1 * 32 + ra, rowb1 = tj1 * 32 + ra;
  f32x16 acc10 = {}, acc20 = {}, acc11 = {}, acc21 = {};
  auto mf = [&](int BUF) {
    {
      bf16x8 a1 = *(const bf16x8*)&sDen[BUF][cc2][rowa0][0];
      bf16x8 b1 = *(const bf16x8*)&sGT[BUF][cc2][rowb0][0];
      bf16x8 a2 = *(const bf16x8*)&sG[BUF][cc2][rowa0][0];
      bf16x8 b2 = *(const bf16x8*)&sVT[BUF][cc2][rowb0][0];
      acc10 = __builtin_amdgcn_mfma_f32_32x32x16_bf16(a1, b1, acc10, 0, 0, 0);
      acc20 = __builtin_amdgcn_mfma_f32_32x32x16_bf16(a2, b2, acc20, 0, 0, 0);
    }
    if (val1t) {
      bf16x8 a1 = *(const bf16x8*)&sDen[BUF][cc2][rowa1][0];
      bf16x8 b1 = *(const bf16x8*)&sGT[BUF][cc2][rowb1][0];
      bf16x8 a2 = *(const bf16x8*)&sG[BUF][cc2][rowa1][0];
      bf16x8 b2 = *(const bf16x8*)&sVT[BUF][cc2][rowb1][0];
      acc11 = __builtin_amdgcn_mfma_f32_32x32x16_bf16(a1, b1, acc11, 0, 0, 0);
      acc21 = __builtin_amdgcn_mfma_f32_32x32x16_bf16(a2, b2, acc21, 0, 0, 0);
    }
  };

  load0(0, vA0); load1(0, vA1);
  load0(1, vB0); load1(1, vB1);
  wr(0, vA0, vA1, d00, d10);
  __syncthreads();
  for (int p = 0; p < NP; p += 2) {
    if (p + 2 < NP) { load0(p + 2, vA0); load1(p + 2, vA1); }
    mf(0);
    wr(p + 1, vB0, vB1, d01, d11);
    wg_barrier();
    if (p + 3 < NP) { load0(p + 3, vB0); load1(p + 3, vB1); }
    mf(1);
    if (p + 2 < NP) wr(p + 2, vA0, vA1, d00, d10);
    wg_barrier();
  }
  float g3 = 0.f;
  #pragma unroll
  for (int r2 = 0; r2 < 16; ++r2) g3 += acc10[r2] * acc20[r2];
  if (val1t) {
    #pragma unroll
    for (int r2 = 0; r2 < 16; ++r2) g3 += acc11[r2] * acc21[r2];
  }
  #pragma unroll
  for (int o = 32; o; o >>= 1) {
    gw1a += __shfl_xor(gw1a, o);
    gw2a += __shfl_xor(gw2a, o);
    g3 += __shfl_xor(g3, o);
  }
  if (lane == 0) { red[wid] = gw1a; red[8 + wid] = gw2a; red[16 + wid] = g3; }
  __syncthreads();
  if (tid == 0) {
    float s1 = 0.f, s2 = 0.f, s3 = 0.f;
    #pragma unroll
    for (int i = 0; i < 8; ++i) { s1 += red[i]; s2 += red[8 + i]; s3 += red[16 + i]; }
    if (h == 0) atomicAdd(acc + 5, s1);
    atomicAdd(acc + 6, s2);
    atomicAdd(acc + 7, s3);
  }
}

__global__ void finalize_k(const float* __restrict__ acc, float* __restrict__ out) {
  if (threadIdx.x == 0) {
    float ce_s = acc[0], ce_e = acc[1], kls = acc[2], kle = acc[3];
    float w = acc[4], gw1 = acc[5], gw2 = acc[6], gw3 = acc[7];
    float spn = acc[8], nans = acc[9];
    float l_qa = (ce_s + ce_e) / (2.f * Bn);
    float l_fgw = (ALPHA * (gw1 + gw2 - 2.f * gw3) + (1.f - ALPHA) * w) / Bn;
    float l_span = (nans > 0.f) ? spn / fmaxf(nans, 1.f) : 0.f;
    float l_cons = 2.f * (kls + kle) / Bn;  // T^2 * ((kls+kle)/B) / 2 with T=2
    float total = l_qa + L_FGW * l_fgw + L_SPAN * l_span + L_CONS * l_cons;
    out[0] = total; out[1] = l_qa; out[2] = l_fgw; out[3] = l_span; out[4] = l_cons;
  }
}

extern "C" void kernel_launch(void* const* d_in, const int* in_sizes, int n_in,
                              void* d_out, int out_size, void* d_ws, size_t ws_size,
                              hipStream_t stream) {
  const float* en  = (const float*)d_in[0];
  const float* vi  = (const float*)d_in[1];
  const float* gam = (const float*)d_in[2];
  const float* Den = (const float*)d_in[3];
  const float* Dvi = (const float*)d_in[4];
  const float* M   = (const float*)d_in[5];
  const int* enst  = (const int*)d_in[6];
  const int* enen  = (const int*)d_in[7];
  const float* w_s = (const float*)d_in[8];
  const float* b_s = (const float*)d_in[9];
  const float* w_e = (const float*)d_in[10];
  const float* b_e = (const float*)d_in[11];
  float* ws = (float*)d_ws;
  float* wsl = ws;                         // 4*BK logits
  float* p_arr = ws + (size_t)4 * BK;      // BK
  float* q_arr = p_arr + BK;               // BK
  float* acc = q_arr + BK;                 // 16 accumulators
  float* out = (float*)d_out;

  qa_logits_k<<<(2 * BK) / 4, 256, 0, stream>>>(en, vi, w_s, b_s, w_e, b_e, wsl, acc);
  stats_logit_k<<<Bn, 512, 0, stream>>>(gam, M, enst, enen, wsl, p_arr, q_arr, acc);
  fgw_k<<<2 * Bn, 512, 0, stream>>>(Den, Dvi, gam, p_arr, q_arr, acc);
  finalize_k<<<1, 64, 0, stream>>>(acc, out);
}

// Round 7
// 159.220 us; speedup vs baseline: 1.4536x; 1.1863x over previous
//
#include <hip/hip_runtime.h>

#define Bn 512
#define Kn 160
#define Hn 256
#define BK (Bn*Kn)
#define ALPHA 0.5f
#define MAX_SPAN 30
#define L_FGW 0.1f
#define L_SPAN 0.5f
#define L_CONS 0.3f
#define KP 16
#define NP 10

typedef __bf16 bf16x8 __attribute__((ext_vector_type(8)));
typedef float f32x16 __attribute__((ext_vector_type(16)));

// raw barrier: LDS drained, global loads stay in flight (no vmcnt drain)
__device__ __forceinline__ void wg_barrier() {
  asm volatile("s_waitcnt lgkmcnt(0)" ::: "memory");
  __builtin_amdgcn_s_barrier();
  __builtin_amdgcn_sched_barrier(0);
}

// ---- QA head logits: one wave per (emb,row); H=256 = 64 lanes x float4 ----
__global__ __launch_bounds__(256) void qa_logits_k(
    const float* __restrict__ en, const float* __restrict__ vi,
    const float* __restrict__ w_s, const float* __restrict__ b_s,
    const float* __restrict__ w_e, const float* __restrict__ b_e,
    float* __restrict__ wsl) {
  int row = blockIdx.x * 4 + (threadIdx.x >> 6);
  int lane = threadIdx.x & 63;
  bool isVi = row >= BK;
  int r = isVi ? row - BK : row;
  const float* emb = isVi ? vi : en;
  float4 v = *(const float4*)(emb + (size_t)r * Hn + lane * 4);
  float4 a = *(const float4*)(w_s + lane * 4);
  float4 c = *(const float4*)(w_e + lane * 4);
  float ds = v.x*a.x + v.y*a.y + v.z*a.z + v.w*a.w;
  float de = v.x*c.x + v.y*c.y + v.z*c.z + v.w*c.w;
  #pragma unroll
  for (int o = 32; o; o >>= 1) { ds += __shfl_xor(ds, o); de += __shfl_xor(de, o); }
  if (lane == 0) {
    size_t base = isVi ? (size_t)2 * BK : 0;
    wsl[base + r] = ds + b_s[0];
    wsl[base + BK + r] = de + b_e[0];
  }
}

// ---- fused: gamma stats (p,q,w) + span decode + QA CE + KL + span CE ----
// No global atomics: per-block scalars plain-stored to sp1[b*8..].
__global__ __launch_bounds__(512) void stats_logit_k(
    const float* __restrict__ gam, const float* __restrict__ M,
    const int* __restrict__ enst, const int* __restrict__ enen,
    const float* __restrict__ wsl, float* __restrict__ p_arr,
    float* __restrict__ q_arr, float* __restrict__ sp1) {
  __shared__ float qsh[Kn];
  __shared__ float vsc[Kn];
  __shared__ float wsh[8];
  __shared__ float bv[512];
  __shared__ int bidx[512];
  __shared__ int pspe[2];
  int b = blockIdx.x, tid = threadIdx.x;
  int wid = tid >> 6, lane = tid & 63;
  for (int t = tid; t < Kn; t += 512) { qsh[t] = 0.f; vsc[t] = 0.f; }
  __syncthreads();
  int s0 = enst[b], e0 = enen[b];
  int s = min(max(s0, 0), Kn - 1);
  int e = max(s, min(max(e0, 0), Kn - 1));
  const float* gb = gam + (size_t)b * Kn * Kn;
  const float* mb = M + (size_t)b * Kn * Kn;
  bool tail = lane < 16;
  float qx = 0.f, qy = 0.f, qz = 0.f, qw = 0.f;
  float vx = 0.f, vy = 0.f, vz = 0.f, vw = 0.f;
  float wloc = 0.f;
  float p20[20];
  #pragma unroll
  for (int it = 0; it < 20; ++it) {
    int i = wid + 8 * it;
    const float2* g2 = (const float2*)(gb + (size_t)i * Kn);
    const float2* m2 = (const float2*)(mb + (size_t)i * Kn);
    float2 gA = g2[lane];
    float2 mA = m2[lane];
    float2 gB = {0.f, 0.f}, mB = {0.f, 0.f};
    if (tail) { gB = g2[64 + lane]; mB = m2[64 + lane]; }
    qx += gA.x; qy += gA.y; qz += gB.x; qw += gB.y;
    wloc += mA.x * gA.x + mA.y * gA.y + mB.x * gB.x + mB.y * gB.y;
    p20[it] = gA.x + gA.y + gB.x + gB.y;   // per-lane partial, reduced later
    float f = (i >= s && i <= e) ? 1.f : 0.f;
    vx += f * gA.x; vy += f * gA.y; vz += f * gB.x; vw += f * gB.y;
  }
  // ---- deferred reductions ----
  #pragma unroll
  for (int it = 0; it < 20; ++it) {
    float rs = p20[it];
    #pragma unroll
    for (int o = 32; o; o >>= 1) rs += __shfl_xor(rs, o);
    if (lane == 0) p_arr[(size_t)b * Kn + wid + 8 * it] = rs;
  }
  atomicAdd(&qsh[2 * lane], qx); atomicAdd(&qsh[2 * lane + 1], qy);
  atomicAdd(&vsc[2 * lane], vx); atomicAdd(&vsc[2 * lane + 1], vy);
  if (tail) {
    atomicAdd(&qsh[128 + 2 * lane], qz); atomicAdd(&qsh[128 + 2 * lane + 1], qw);
    atomicAdd(&vsc[128 + 2 * lane], vz); atomicAdd(&vsc[128 + 2 * lane + 1], vw);
  }
  #pragma unroll
  for (int o = 32; o; o >>= 1) wloc += __shfl_xor(wloc, o);
  if (lane == 0) wsh[wid] = wloc;
  __syncthreads();
  if (tid < Kn) q_arr[(size_t)b * Kn + tid] = qsh[tid];
  if (tid == 0) {
    float sw = 0.f;
    #pragma unroll
    for (int i2 = 0; i2 < 8; ++i2) sw += wsh[i2];
    sp1[(size_t)b * 8 + 4] = sw;
  }
  // ---- span argmax (first-max semantics) ----
  float best = -1e30f;
  int bfl = 0x7fffffff;
  if (tid < Kn) {
    float vsi = vsc[tid];
    int hi = min(tid + MAX_SPAN, Kn - 1);
    for (int ei = tid; ei <= hi; ++ei) {
      float v = vsi + vsc[ei];
      if (v > best) { best = v; bfl = tid * Kn + ei; }
    }
  }
  bv[tid] = best; bidx[tid] = bfl;
  for (int st = 256; st > 0; st >>= 1) {
    __syncthreads();
    if (tid < st) {
      float v2 = bv[tid + st]; int i2 = bidx[tid + st];
      if (v2 > bv[tid] || (v2 == bv[tid] && i2 < bidx[tid])) { bv[tid] = v2; bidx[tid] = i2; }
    }
  }
  if (tid == 0) {
    int fl = bidx[0];
    int ps = fl / Kn, pe = fl - (fl / Kn) * Kn;
    if (s0 == 0 && e0 == 0) { ps = 0; pe = 0; }
    pspe[0] = ps; pspe[1] = pe;
  }
  __syncthreads();
  // ---- logit losses: wave 0 only ----
  if (wid == 0) {
    const float* es = wsl + (size_t)b * Kn;
    const float* ee = wsl + (size_t)BK + (size_t)b * Kn;
    const float* vs = wsl + (size_t)2 * BK + (size_t)b * Kn;
    const float* ve = wsl + (size_t)3 * BK + (size_t)b * Kn;
    float xes[3], xee[3], xvs[3], xve[3];
    #pragma unroll
    for (int j = 0; j < 3; ++j) {
      int idx = lane + 64 * j;
      bool val = idx < Kn;
      xes[j] = val ? es[idx] : -1e30f;
      xee[j] = val ? ee[idx] : -1e30f;
      xvs[j] = val ? vs[idx] : -1e30f;
      xve[j] = val ? ve[idx] : -1e30f;
    }
    auto wlse = [&](float x0, float x1, float x2) -> float {
      float m = fmaxf(fmaxf(x0, x1), x2);
      #pragma unroll
      for (int o = 32; o; o >>= 1) m = fmaxf(m, __shfl_xor(m, o));
      float su = expf(x0 - m) + expf(x1 - m) + expf(x2 - m);
      #pragma unroll
      for (int o = 32; o; o >>= 1) su += __shfl_xor(su, o);
      return m + logf(su);
    };
    float l_es = wlse(xes[0], xes[1], xes[2]);
    float l_ee = wlse(xee[0], xee[1], xee[2]);
    float l_vs = wlse(xvs[0], xvs[1], xvs[2]);
    float l_ve = wlse(xve[0], xve[1], xve[2]);
    float lT_es = wlse(xes[0]*0.5f, xes[1]*0.5f, xes[2]*0.5f);
    float lT_ee = wlse(xee[0]*0.5f, xee[1]*0.5f, xee[2]*0.5f);
    float lT_vs = wlse(xvs[0]*0.5f, xvs[1]*0.5f, xvs[2]*0.5f);
    float lT_ve = wlse(xve[0]*0.5f, xve[1]*0.5f, xve[2]*0.5f);
    float kls = 0.f, kle = 0.f;
    #pragma unroll
    for (int j = 0; j < 3; ++j) {
      int idx = lane + 64 * j;
      if (idx < Kn) {
        float aa = xes[j]*0.5f - lT_es;
        float bb = xvs[j]*0.5f - lT_vs;
        kls += expf(aa) * (aa - bb);
        float cc = xee[j]*0.5f - lT_ee;
        float dd = xve[j]*0.5f - lT_ve;
        kle += expf(cc) * (cc - dd);
      }
    }
    #pragma unroll
    for (int o = 32; o; o >>= 1) { kls += __shfl_xor(kls, o); kle += __shfl_xor(kle, o); }
    if (lane == 0) {
      int sl = min(max(s0, 0), Kn - 1);
      int el = min(max(e0, 0), Kn - 1);
      float* o = sp1 + (size_t)b * 8;
      o[0] = l_es - es[sl];
      o[1] = l_ee - ee[el];
      o[2] = kls;
      o[3] = kle;
      bool answerable = (s0 > 0) || (e0 > 0);
      float ce = 0.5f * ((l_vs - vs[pspe[0]]) + (l_ve - ve[pspe[1]]));
      o[5] = answerable ? ce : 0.f;
      o[6] = answerable ? 1.f : 0.f;
    }
  }
}

// ---- MFMA FGW, software-pipelined; per-block results plain-stored to sp2 ----
__global__ __launch_bounds__(512, 3) void fgw_k(
    const float* __restrict__ Den, const float* __restrict__ Dvi,
    const float* __restrict__ gam, const float* __restrict__ p_arr,
    const float* __restrict__ q_arr, float* __restrict__ sp2) {
  __shared__ __align__(16) __bf16 sDen[2][2][Kn][8];
  __shared__ __align__(16) __bf16 sG  [2][2][Kn][8];
  __shared__ __align__(16) __bf16 sGT [2][2][96][8];
  __shared__ __align__(16) __bf16 sVT [2][2][96][8];
  __shared__ float pq[2 * Kn];
  __shared__ float red[24];
  int bid = blockIdx.x;
  int h = (bid >> 3) & 1;
  int b = ((bid >> 4) << 3) | (bid & 7);
  const int JB = h ? 96 : 0;
  const int NBJ = h ? 64 : 96;
  const int NTJ = h ? 2 : 3;
  const int NT = 5 * NTJ;
  int tid = threadIdx.x;
  int wid = tid >> 6, lane = tid & 63;
  const float* den_b = Den + (size_t)b * Kn * Kn;
  const float* dvi_b = Dvi + (size_t)b * Kn * Kn;
  const float* gam_b = gam + (size_t)b * Kn * Kn;
  if (tid < 2 * Kn)
    pq[tid] = (tid < Kn) ? p_arr[(size_t)b * Kn + tid]
                         : q_arr[(size_t)b * Kn + (tid - Kn)];
  __syncthreads();

  // slot0 (tau=tid, 0..511): always row-major. tau<320 -> sDen, else sG.
  int op0 = tid >= 320 ? 1 : 0;
  int f0 = tid - 320 * op0;
  int c0 = f0 >= Kn ? 1 : 0;
  int r0 = f0 - Kn * c0;
  const float* s0p = (op0 ? gam_b : den_b) + (size_t)r0 * Kn + 8 * c0;
  __bf16* d00 = op0 ? &sG[0][c0][r0][0] : &sDen[0][c0][r0][0];
  __bf16* d01 = op0 ? &sG[1][c0][r0][0] : &sDen[1][c0][r0][0];
  int gw1k = (!op0 && h == 0) ? 1 : 0;
  float wgt0 = gw1k ? pq[r0] : 0.f;
  const float* pqb0 = pq + 8 * c0;
  // slot1 (tau=tid+512): tid<128 -> row-major (sG,c=1,r=tid+32); else transposed.
  bool rm1 = tid < 128;
  bool act1 = (tid + 512) < (640 + 4 * NBJ);
  const float* s1p = den_b;
  __bf16* d10 = &sGT[0][0][0][0];
  __bf16* d11 = &sGT[1][0][0][0];
  int gw2k = 0;
  float wgt1 = 0.f;
  const float* pqb1 = pq;
  if (act1) {
    if (rm1) {
      int r1 = tid + 32;
      s1p = gam_b + (size_t)r1 * Kn + 8;
      d10 = &sG[0][1][r1][0];
      d11 = &sG[1][1][r1][0];
    } else {
      int f2 = tid - 128;
      int op1 = f2 >= 2 * NBJ ? 1 : 0;
      int f = f2 - 2 * NBJ * op1;
      int c1 = f >= NBJ ? 1 : 0;
      int r1 = f - NBJ * c1;
      int j = JB + r1;
      s1p = (op1 ? dvi_b : gam_b) + (size_t)(8 * c1) * Kn + j;
      d10 = op1 ? &sVT[0][c1][r1][0] : &sGT[0][c1][r1][0];
      d11 = op1 ? &sVT[1][c1][r1][0] : &sGT[1][c1][r1][0];
      if (op1) { gw2k = 1; wgt1 = pq[Kn + j]; pqb1 = pq + Kn + 8 * c1; }
    }
  }
  float gw1a = 0.f, gw2a = 0.f;
  float vA0[8], vA1[8], vB0[8], vB1[8];

  auto load0 = [&](int p, float* v) {
    const float* sp = s0p + p * KP;
    float4 x = *(const float4*)sp;
    float4 y = *(const float4*)(sp + 4);
    v[0]=x.x; v[1]=x.y; v[2]=x.z; v[3]=x.w;
    v[4]=y.x; v[5]=y.y; v[6]=y.z; v[7]=y.w;
  };
  auto load1 = [&](int p, float* v) {
    if (!act1) return;
    if (rm1) {
      const float* sp = s1p + p * KP;
      float4 x = *(const float4*)sp;
      float4 y = *(const float4*)(sp + 4);
      v[0]=x.x; v[1]=x.y; v[2]=x.z; v[3]=x.w;
      v[4]=y.x; v[5]=y.y; v[6]=y.z; v[7]=y.w;
    } else {
      const float* sp = s1p + (size_t)p * KP * Kn;
      #pragma unroll
      for (int e2 = 0; e2 < 8; ++e2) v[e2] = sp[(size_t)e2 * Kn];
    }
  };
  auto wr = [&](int p, const float* v0, const float* v1, __bf16* w0, __bf16* w1) {
    if (gw1k) {
      const float* pp = pqb0 + p * KP;
      float g = 0.f;
      #pragma unroll
      for (int e2 = 0; e2 < 8; ++e2) g += v0[e2] * v0[e2] * pp[e2];
      gw1a += g * wgt0;
    }
    bf16x8 wv;
    #pragma unroll
    for (int e2 = 0; e2 < 8; ++e2) wv[e2] = (__bf16)v0[e2];
    *(bf16x8*)w0 = wv;
    if (act1) {
      if (gw2k) {
        const float* pp = pqb1 + p * KP;
        float g = 0.f;
        #pragma unroll
        for (int e2 = 0; e2 < 8; ++e2) g += v1[e2] * v1[e2] * pp[e2];
        gw2a += g * wgt1;
      }
      bf16x8 wv2;
      #pragma unroll
      for (int e2 = 0; e2 < 8; ++e2) wv2[e2] = (__bf16)v1[e2];
      *(bf16x8*)w1 = wv2;
    }
  };

  int ra = lane & 31, cc2 = lane >> 5;
  int t1i = wid + 8;
  bool val1t = t1i < NT;
  int ti0 = wid / NTJ, tj0 = wid - ti0 * NTJ;
  int rowa0 = ti0 * 32 + ra, rowb0 = tj0 * 32 + ra;
  int ti1 = t1i / NTJ, tj1 = t1i - ti1 * NTJ;
  int rowa1 = ti1 * 32 + ra, rowb1 = tj1 * 32 + ra;
  f32x16 acc10 = {}, acc20 = {}, acc11 = {}, acc21 = {};
  auto mf = [&](int BUF) {
    {
      bf16x8 a1 = *(const bf16x8*)&sDen[BUF][cc2][rowa0][0];
      bf16x8 b1 = *(const bf16x8*)&sGT[BUF][cc2][rowb0][0];
      bf16x8 a2 = *(const bf16x8*)&sG[BUF][cc2][rowa0][0];
      bf16x8 b2 = *(const bf16x8*)&sVT[BUF][cc2][rowb0][0];
      acc10 = __builtin_amdgcn_mfma_f32_32x32x16_bf16(a1, b1, acc10, 0, 0, 0);
      acc20 = __builtin_amdgcn_mfma_f32_32x32x16_bf16(a2, b2, acc20, 0, 0, 0);
    }
    if (val1t) {
      bf16x8 a1 = *(const bf16x8*)&sDen[BUF][cc2][rowa1][0];
      bf16x8 b1 = *(const bf16x8*)&sGT[BUF][cc2][rowb1][0];
      bf16x8 a2 = *(const bf16x8*)&sG[BUF][cc2][rowa1][0];
      bf16x8 b2 = *(const bf16x8*)&sVT[BUF][cc2][rowb1][0];
      acc11 = __builtin_amdgcn_mfma_f32_32x32x16_bf16(a1, b1, acc11, 0, 0, 0);
      acc21 = __builtin_amdgcn_mfma_f32_32x32x16_bf16(a2, b2, acc21, 0, 0, 0);
    }
  };

  load0(0, vA0); load1(0, vA1);
  load0(1, vB0); load1(1, vB1);
  wr(0, vA0, vA1, d00, d10);
  __syncthreads();
  for (int p = 0; p < NP; p += 2) {
    if (p + 2 < NP) { load0(p + 2, vA0); load1(p + 2, vA1); }
    mf(0);
    wr(p + 1, vB0, vB1, d01, d11);
    wg_barrier();
    if (p + 3 < NP) { load0(p + 3, vB0); load1(p + 3, vB1); }
    mf(1);
    if (p + 2 < NP) wr(p + 2, vA0, vA1, d00, d10);
    wg_barrier();
  }
  float g3 = 0.f;
  #pragma unroll
  for (int r2 = 0; r2 < 16; ++r2) g3 += acc10[r2] * acc20[r2];
  if (val1t) {
    #pragma unroll
    for (int r2 = 0; r2 < 16; ++r2) g3 += acc11[r2] * acc21[r2];
  }
  #pragma unroll
  for (int o = 32; o; o >>= 1) {
    gw1a += __shfl_xor(gw1a, o);
    gw2a += __shfl_xor(gw2a, o);
    g3 += __shfl_xor(g3, o);
  }
  if (lane == 0) { red[wid] = gw1a; red[8 + wid] = gw2a; red[16 + wid] = g3; }
  __syncthreads();
  if (tid == 0) {
    float s1 = 0.f, s2 = 0.f, s3 = 0.f;
    #pragma unroll
    for (int i = 0; i < 8; ++i) { s1 += red[i]; s2 += red[8 + i]; s3 += red[16 + i]; }
    float* o = sp2 + (size_t)bid * 4;
    o[0] = s1; o[1] = s2; o[2] = s3;
  }
}

// ---- final reduction of per-block slabs (no atomics anywhere) ----
__global__ __launch_bounds__(512) void finalize_k(
    const float* __restrict__ sp1, const float* __restrict__ sp2,
    float* __restrict__ out) {
  __shared__ float red[8][10];
  int tid = threadIdx.x;
  int wid = tid >> 6, lane = tid & 63;
  float v[10];
  const float* a = sp1 + (size_t)tid * 8;
  #pragma unroll
  for (int i = 0; i < 7; ++i) v[i] = a[i];
  const float* b0 = sp2 + (size_t)(2 * tid) * 4;
  const float* b1 = sp2 + (size_t)(2 * tid + 1) * 4;
  v[7] = b0[0] + b1[0];
  v[8] = b0[1] + b1[1];
  v[9] = b0[2] + b1[2];
  #pragma unroll
  for (int i = 0; i < 10; ++i) {
    float s = v[i];
    #pragma unroll
    for (int o = 32; o; o >>= 1) s += __shfl_xor(s, o);
    v[i] = s;
  }
  if (lane == 0) {
    #pragma unroll
    for (int i = 0; i < 10; ++i) red[wid][i] = v[i];
  }
  __syncthreads();
  if (tid == 0) {
    float t[10];
    #pragma unroll
    for (int i = 0; i < 10; ++i) {
      float s = 0.f;
      #pragma unroll
      for (int w2 = 0; w2 < 8; ++w2) s += red[w2][i];
      t[i] = s;
    }
    float ce_s = t[0], ce_e = t[1], kls = t[2], kle = t[3];
    float w = t[4], spn = t[5], nans = t[6];
    float gw1 = t[7], gw2 = t[8], gw3 = t[9];
    float l_qa = (ce_s + ce_e) / (2.f * Bn);
    float l_fgw = (ALPHA * (gw1 + gw2 - 2.f * gw3) + (1.f - ALPHA) * w) / Bn;
    float l_span = (nans > 0.f) ? spn / fmaxf(nans, 1.f) : 0.f;
    float l_cons = 2.f * (kls + kle) / Bn;  // T^2 * ((kls+kle)/B) / 2 with T=2
    float total = l_qa + L_FGW * l_fgw + L_SPAN * l_span + L_CONS * l_cons;
    out[0] = total; out[1] = l_qa; out[2] = l_fgw; out[3] = l_span; out[4] = l_cons;
  }
}

extern "C" void kernel_launch(void* const* d_in, const int* in_sizes, int n_in,
                              void* d_out, int out_size, void* d_ws, size_t ws_size,
                              hipStream_t stream) {
  const float* en  = (const float*)d_in[0];
  const float* vi  = (const float*)d_in[1];
  const float* gam = (const float*)d_in[2];
  const float* Den = (const float*)d_in[3];
  const float* Dvi = (const float*)d_in[4];
  const float* M   = (const float*)d_in[5];
  const int* enst  = (const int*)d_in[6];
  const int* enen  = (const int*)d_in[7];
  const float* w_s = (const float*)d_in[8];
  const float* b_s = (const float*)d_in[9];
  const float* w_e = (const float*)d_in[10];
  const float* b_e = (const float*)d_in[11];
  float* ws = (float*)d_ws;
  float* wsl = ws;                         // 4*BK logits
  float* p_arr = ws + (size_t)4 * BK;      // BK
  float* q_arr = p_arr + BK;               // BK
  float* sp1 = q_arr + BK;                 // 512*8 stats partials
  float* sp2 = sp1 + 8 * Bn;               // 1024*4 fgw partials
  float* out = (float*)d_out;

  qa_logits_k<<<(2 * BK) / 4, 256, 0, stream>>>(en, vi, w_s, b_s, w_e, b_e, wsl);
  stats_logit_k<<<Bn, 512, 0, stream>>>(gam, M, enst, enen, wsl, p_arr, q_arr, sp1);
  fgw_k<<<2 * Bn, 512, 0, stream>>>(Den, Dvi, gam, p_arr, q_arr, sp2);
  finalize_k<<<1, 512, 0, stream>>>(sp1, sp2, out);
}

// Round 8
// 149.948 us; speedup vs baseline: 1.5434x; 1.0618x over previous
//
#include <hip/hip_runtime.h>

#define Bn 512
#define Kn 160
#define Hn 256
#define BK (Bn*Kn)
#define ALPHA 0.5f
#define MAX_SPAN 30
#define L_FGW 0.1f
#define L_SPAN 0.5f
#define L_CONS 0.3f
#define KP 16
#define NP 10

typedef __bf16 bf16x8 __attribute__((ext_vector_type(8)));
typedef float f32x16 __attribute__((ext_vector_type(16)));
typedef float f32x4v __attribute__((ext_vector_type(4)));
typedef float f32x2v __attribute__((ext_vector_type(2)));

// raw barrier: LDS drained, global loads stay in flight (no vmcnt drain)
__device__ __forceinline__ void wg_barrier() {
  asm volatile("s_waitcnt lgkmcnt(0)" ::: "memory");
  __builtin_amdgcn_s_barrier();
  __builtin_amdgcn_sched_barrier(0);
}

// ---- QA head logits: one wave per (emb,row); H=256 = 64 lanes x float4 ----
// emb loads are non-temporal: en/vi are dead after this kernel; keep L3 for
// gamma/M/D_en/D_vi which later kernels re-read.
__global__ __launch_bounds__(256) void qa_logits_k(
    const float* __restrict__ en, const float* __restrict__ vi,
    const float* __restrict__ w_s, const float* __restrict__ b_s,
    const float* __restrict__ w_e, const float* __restrict__ b_e,
    float* __restrict__ wsl) {
  int row = blockIdx.x * 4 + (threadIdx.x >> 6);
  int lane = threadIdx.x & 63;
  bool isVi = row >= BK;
  int r = isVi ? row - BK : row;
  const float* emb = isVi ? vi : en;
  f32x4v v = __builtin_nontemporal_load((const f32x4v*)(emb + (size_t)r * Hn + lane * 4));
  float4 a = *(const float4*)(w_s + lane * 4);
  float4 c = *(const float4*)(w_e + lane * 4);
  float ds = v[0]*a.x + v[1]*a.y + v[2]*a.z + v[3]*a.w;
  float de = v[0]*c.x + v[1]*c.y + v[2]*c.z + v[3]*c.w;
  #pragma unroll
  for (int o = 32; o; o >>= 1) { ds += __shfl_xor(ds, o); de += __shfl_xor(de, o); }
  if (lane == 0) {
    size_t base = isVi ? (size_t)2 * BK : 0;
    wsl[base + r] = ds + b_s[0];
    wsl[base + BK + r] = de + b_e[0];
  }
}

// ---- fused: gamma stats (p,q,w) + gw1 (D_en, needs p) + gw2 (D_vi, needs q)
//      + span decode + QA CE + KL + span CE. One block per batch.
// The D_en/D_vi passes double as L3 warm-up for fgw_k (which runs next).
// M is non-temporal (dead after this kernel).
__global__ __launch_bounds__(512) void stats_k(
    const float* __restrict__ gam, const float* __restrict__ M,
    const float* __restrict__ Den, const float* __restrict__ Dvi,
    const int* __restrict__ enst, const int* __restrict__ enen,
    const float* __restrict__ wsl, float* __restrict__ sp1) {
  __shared__ float psh[Kn];
  __shared__ float qsh[Kn];
  __shared__ float vsc[Kn];
  __shared__ float wsh[8];
  __shared__ float g1sh[8];
  __shared__ float g2sh[8];
  __shared__ float bv[512];
  __shared__ int bidx[512];
  __shared__ int pspe[2];
  int b = blockIdx.x, tid = threadIdx.x;
  int wid = tid >> 6, lane = tid & 63;
  for (int t = tid; t < Kn; t += 512) { qsh[t] = 0.f; vsc[t] = 0.f; }
  __syncthreads();
  int s0 = enst[b], e0 = enen[b];
  int s = min(max(s0, 0), Kn - 1);
  int e = max(s, min(max(e0, 0), Kn - 1));
  const float* gb = gam + (size_t)b * Kn * Kn;
  const float* mb = M + (size_t)b * Kn * Kn;
  const float* db = Den + (size_t)b * Kn * Kn;
  const float* vb = Dvi + (size_t)b * Kn * Kn;
  bool tail = lane < 16;
  float qx = 0.f, qy = 0.f, qz = 0.f, qw = 0.f;
  float vx = 0.f, vy = 0.f, vz = 0.f, vw = 0.f;
  float wloc = 0.f;
  float p20[20];
  #pragma unroll
  for (int it = 0; it < 20; ++it) {
    int i = wid + 8 * it;
    const float2* g2 = (const float2*)(gb + (size_t)i * Kn);
    const f32x2v* m2 = (const f32x2v*)(mb + (size_t)i * Kn);
    float2 gA = g2[lane];
    f32x2v mA = __builtin_nontemporal_load(m2 + lane);
    float2 gB = {0.f, 0.f};
    f32x2v mB = {0.f, 0.f};
    if (tail) { gB = g2[64 + lane]; mB = __builtin_nontemporal_load(m2 + 64 + lane); }
    qx += gA.x; qy += gA.y; qz += gB.x; qw += gB.y;
    wloc += mA[0] * gA.x + mA[1] * gA.y + mB[0] * gB.x + mB[1] * gB.y;
    p20[it] = gA.x + gA.y + gB.x + gB.y;   // per-lane partial, reduced later
    float f = (i >= s && i <= e) ? 1.f : 0.f;
    vx += f * gA.x; vy += f * gA.y; vz += f * gB.x; vw += f * gB.y;
  }
  // ---- deferred reductions ----
  #pragma unroll
  for (int it = 0; it < 20; ++it) {
    float rs = p20[it];
    #pragma unroll
    for (int o = 32; o; o >>= 1) rs += __shfl_xor(rs, o);
    if (lane == 0) psh[wid + 8 * it] = rs;
  }
  atomicAdd(&qsh[2 * lane], qx); atomicAdd(&qsh[2 * lane + 1], qy);
  atomicAdd(&vsc[2 * lane], vx); atomicAdd(&vsc[2 * lane + 1], vy);
  if (tail) {
    atomicAdd(&qsh[128 + 2 * lane], qz); atomicAdd(&qsh[128 + 2 * lane + 1], qw);
    atomicAdd(&vsc[128 + 2 * lane], vz); atomicAdd(&vsc[128 + 2 * lane + 1], vw);
  }
  #pragma unroll
  for (int o = 32; o; o >>= 1) wloc += __shfl_xor(wloc, o);
  if (lane == 0) wsh[wid] = wloc;
  __syncthreads();
  // ---- gw1 / gw2 passes (p,q now final in LDS); also warms D_en/D_vi in L3 ----
  float pA0 = psh[2 * lane], pA1 = psh[2 * lane + 1];
  float pB0 = tail ? psh[128 + 2 * lane] : 0.f;
  float pB1 = tail ? psh[128 + 2 * lane + 1] : 0.f;
  float qA0 = qsh[2 * lane], qA1 = qsh[2 * lane + 1];
  float qB0 = tail ? qsh[128 + 2 * lane] : 0.f;
  float qB1 = tail ? qsh[128 + 2 * lane + 1] : 0.f;
  float g1loc = 0.f, g2loc = 0.f;
  #pragma unroll 4
  for (int it = 0; it < 20; ++it) {
    int i = wid + 8 * it;
    const float2* d2 = (const float2*)(db + (size_t)i * Kn);
    float2 dA = d2[lane];
    float2 dB = {0.f, 0.f};
    if (tail) dB = d2[64 + lane];
    float rd = dA.x*dA.x*pA0 + dA.y*dA.y*pA1 + dB.x*dB.x*pB0 + dB.y*dB.y*pB1;
    g1loc += psh[i] * rd;
    const float2* v2 = (const float2*)(vb + (size_t)i * Kn);
    float2 vA = v2[lane];
    float2 vB = {0.f, 0.f};
    if (tail) vB = v2[64 + lane];
    float rv = vA.x*vA.x*qA0 + vA.y*vA.y*qA1 + vB.x*vB.x*qB0 + vB.y*vB.y*qB1;
    g2loc += qsh[i] * rv;
  }
  #pragma unroll
  for (int o = 32; o; o >>= 1) { g1loc += __shfl_xor(g1loc, o); g2loc += __shfl_xor(g2loc, o); }
  if (lane == 0) { g1sh[wid] = g1loc; g2sh[wid] = g2loc; }
  __syncthreads();
  if (tid == 0) {
    float sw = 0.f, s1 = 0.f, s2 = 0.f;
    #pragma unroll
    for (int i2 = 0; i2 < 8; ++i2) { sw += wsh[i2]; s1 += g1sh[i2]; s2 += g2sh[i2]; }
    float* o = sp1 + (size_t)b * 12;
    o[4] = sw; o[7] = s1; o[8] = s2;
  }
  // ---- span argmax (first-max semantics) ----
  float best = -1e30f;
  int bfl = 0x7fffffff;
  if (tid < Kn) {
    float vsi = vsc[tid];
    int hi = min(tid + MAX_SPAN, Kn - 1);
    for (int ei = tid; ei <= hi; ++ei) {
      float v = vsi + vsc[ei];
      if (v > best) { best = v; bfl = tid * Kn + ei; }
    }
  }
  bv[tid] = best; bidx[tid] = bfl;
  for (int st = 256; st > 0; st >>= 1) {
    __syncthreads();
    if (tid < st) {
      float v2 = bv[tid + st]; int i2 = bidx[tid + st];
      if (v2 > bv[tid] || (v2 == bv[tid] && i2 < bidx[tid])) { bv[tid] = v2; bidx[tid] = i2; }
    }
  }
  if (tid == 0) {
    int fl = bidx[0];
    int ps = fl / Kn, pe = fl - (fl / Kn) * Kn;
    if (s0 == 0 && e0 == 0) { ps = 0; pe = 0; }
    pspe[0] = ps; pspe[1] = pe;
  }
  __syncthreads();
  // ---- logit losses: wave 0 only ----
  if (wid == 0) {
    const float* es = wsl + (size_t)b * Kn;
    const float* ee = wsl + (size_t)BK + (size_t)b * Kn;
    const float* vs = wsl + (size_t)2 * BK + (size_t)b * Kn;
    const float* ve = wsl + (size_t)3 * BK + (size_t)b * Kn;
    float xes[3], xee[3], xvs[3], xve[3];
    #pragma unroll
    for (int j = 0; j < 3; ++j) {
      int idx = lane + 64 * j;
      bool val = idx < Kn;
      xes[j] = val ? es[idx] : -1e30f;
      xee[j] = val ? ee[idx] : -1e30f;
      xvs[j] = val ? vs[idx] : -1e30f;
      xve[j] = val ? ve[idx] : -1e30f;
    }
    auto wlse = [&](float x0, float x1, float x2) -> float {
      float m = fmaxf(fmaxf(x0, x1), x2);
      #pragma unroll
      for (int o = 32; o; o >>= 1) m = fmaxf(m, __shfl_xor(m, o));
      float su = expf(x0 - m) + expf(x1 - m) + expf(x2 - m);
      #pragma unroll
      for (int o = 32; o; o >>= 1) su += __shfl_xor(su, o);
      return m + logf(su);
    };
    float l_es = wlse(xes[0], xes[1], xes[2]);
    float l_ee = wlse(xee[0], xee[1], xee[2]);
    float l_vs = wlse(xvs[0], xvs[1], xvs[2]);
    float l_ve = wlse(xve[0], xve[1], xve[2]);
    float lT_es = wlse(xes[0]*0.5f, xes[1]*0.5f, xes[2]*0.5f);
    float lT_ee = wlse(xee[0]*0.5f, xee[1]*0.5f, xee[2]*0.5f);
    float lT_vs = wlse(xvs[0]*0.5f, xvs[1]*0.5f, xvs[2]*0.5f);
    float lT_ve = wlse(xve[0]*0.5f, xve[1]*0.5f, xve[2]*0.5f);
    float kls = 0.f, kle = 0.f;
    #pragma unroll
    for (int j = 0; j < 3; ++j) {
      int idx = lane + 64 * j;
      if (idx < Kn) {
        float aa = xes[j]*0.5f - lT_es;
        float bb = xvs[j]*0.5f - lT_vs;
        kls += expf(aa) * (aa - bb);
        float cc = xee[j]*0.5f - lT_ee;
        float dd = xve[j]*0.5f - lT_ve;
        kle += expf(cc) * (cc - dd);
      }
    }
    #pragma unroll
    for (int o = 32; o; o >>= 1) { kls += __shfl_xor(kls, o); kle += __shfl_xor(kle, o); }
    if (lane == 0) {
      int sl = min(max(s0, 0), Kn - 1);
      int el = min(max(e0, 0), Kn - 1);
      float* o = sp1 + (size_t)b * 12;
      o[0] = l_es - es[sl];
      o[1] = l_ee - ee[el];
      o[2] = kls;
      o[3] = kle;
      bool answerable = (s0 > 0) || (e0 > 0);
      float ce = 0.5f * ((l_vs - vs[pspe[0]]) + (l_ve - ve[pspe[1]]));
      o[5] = answerable ? ce : 0.f;
      o[6] = answerable ? 1.f : 0.f;
    }
  }
}

// ---- MFMA FGW, pure gw3 (gw1/gw2/p/q moved to stats_k). All operand reads
// are L3-warm (stats_k just streamed D_en/D_vi/gamma). Software-pipelined,
// raw lgkm-only barriers. 2 blocks/batch (column halves).
__global__ __launch_bounds__(512) void fgw_k(
    const float* __restrict__ Den, const float* __restrict__ Dvi,
    const float* __restrict__ gam, float* __restrict__ sp2) {
  __shared__ __align__(16) __bf16 sDen[2][2][Kn][8];
  __shared__ __align__(16) __bf16 sG  [2][2][Kn][8];
  __shared__ __align__(16) __bf16 sGT [2][2][96][8];
  __shared__ __align__(16) __bf16 sVT [2][2][96][8];
  __shared__ float red[8];
  int bid = blockIdx.x;
  int h = (bid >> 3) & 1;
  int b = ((bid >> 4) << 3) | (bid & 7);
  const int JB = h ? 96 : 0;
  const int NBJ = h ? 64 : 96;
  const int NTJ = h ? 2 : 3;
  const int NT = 5 * NTJ;
  int tid = threadIdx.x;
  int wid = tid >> 6, lane = tid & 63;
  const float* den_b = Den + (size_t)b * Kn * Kn;
  const float* dvi_b = Dvi + (size_t)b * Kn * Kn;
  const float* gam_b = gam + (size_t)b * Kn * Kn;

  // slot0 (tau=tid, 0..511): always row-major. tau<320 -> sDen, else sG.
  int op0 = tid >= 320 ? 1 : 0;
  int f0 = tid - 320 * op0;
  int c0 = f0 >= Kn ? 1 : 0;
  int r0 = f0 - Kn * c0;
  const float* s0p = (op0 ? gam_b : den_b) + (size_t)r0 * Kn + 8 * c0;
  __bf16* d00 = op0 ? &sG[0][c0][r0][0] : &sDen[0][c0][r0][0];
  __bf16* d01 = op0 ? &sG[1][c0][r0][0] : &sDen[1][c0][r0][0];
  // slot1 (tau=tid+512): tid<128 -> row-major (sG,c=1,r=tid+32); else transposed.
  bool rm1 = tid < 128;
  bool act1 = (tid + 512) < (640 + 4 * NBJ);
  const float* s1p = den_b;
  __bf16* d10 = &sGT[0][0][0][0];
  __bf16* d11 = &sGT[1][0][0][0];
  if (act1) {
    if (rm1) {
      int r1 = tid + 32;
      s1p = gam_b + (size_t)r1 * Kn + 8;
      d10 = &sG[0][1][r1][0];
      d11 = &sG[1][1][r1][0];
    } else {
      int f2 = tid - 128;
      int op1 = f2 >= 2 * NBJ ? 1 : 0;
      int f = f2 - 2 * NBJ * op1;
      int c1 = f >= NBJ ? 1 : 0;
      int r1 = f - NBJ * c1;
      int j = JB + r1;
      s1p = (op1 ? dvi_b : gam_b) + (size_t)(8 * c1) * Kn + j;
      d10 = op1 ? &sVT[0][c1][r1][0] : &sGT[0][c1][r1][0];
      d11 = op1 ? &sVT[1][c1][r1][0] : &sGT[1][c1][r1][0];
    }
  }
  float vA0[8], vA1[8], vB0[8], vB1[8];

  auto load0 = [&](int p, float* v) {
    const float* sp = s0p + p * KP;
    float4 x = *(const float4*)sp;
    float4 y = *(const float4*)(sp + 4);
    v[0]=x.x; v[1]=x.y; v[2]=x.z; v[3]=x.w;
    v[4]=y.x; v[5]=y.y; v[6]=y.z; v[7]=y.w;
  };
  auto load1 = [&](int p, float* v) {
    if (!act1) return;
    if (rm1) {
      const float* sp = s1p + p * KP;
      float4 x = *(const float4*)sp;
      float4 y = *(const float4*)(sp + 4);
      v[0]=x.x; v[1]=x.y; v[2]=x.z; v[3]=x.w;
      v[4]=y.x; v[5]=y.y; v[6]=y.z; v[7]=y.w;
    } else {
      const float* sp = s1p + (size_t)p * KP * Kn;
      #pragma unroll
      for (int e2 = 0; e2 < 8; ++e2) v[e2] = sp[(size_t)e2 * Kn];
    }
  };
  auto wr = [&](const float* v0, const float* v1, __bf16* w0, __bf16* w1) {
    bf16x8 wv;
    #pragma unroll
    for (int e2 = 0; e2 < 8; ++e2) wv[e2] = (__bf16)v0[e2];
    *(bf16x8*)w0 = wv;
    if (act1) {
      bf16x8 wv2;
      #pragma unroll
      for (int e2 = 0; e2 < 8; ++e2) wv2[e2] = (__bf16)v1[e2];
      *(bf16x8*)w1 = wv2;
    }
  };

  int ra = lane & 31, cc2 = lane >> 5;
  int t1i = wid + 8;
  bool val1t = t1i < NT;
  int ti0 = wid / NTJ, tj0 = wid - ti0 * NTJ;
  int rowa0 = ti0 * 32 + ra, rowb0 = tj0 * 32 + ra;
  int ti1 = t1i / NTJ, tj1 = t1i - ti1 * NTJ;
  int rowa1 = ti1 * 32 + ra, rowb1 = tj1 * 32 + ra;
  f32x16 acc10 = {}, acc20 = {}, acc11 = {}, acc21 = {};
  auto mf = [&](int BUF) {
    {
      bf16x8 a1 = *(const bf16x8*)&sDen[BUF][cc2][rowa0][0];
      bf16x8 b1 = *(const bf16x8*)&sGT[BUF][cc2][rowb0][0];
      bf16x8 a2 = *(const bf16x8*)&sG[BUF][cc2][rowa0][0];
      bf16x8 b2 = *(const bf16x8*)&sVT[BUF][cc2][rowb0][0];
      acc10 = __builtin_amdgcn_mfma_f32_32x32x16_bf16(a1, b1, acc10, 0, 0, 0);
      acc20 = __builtin_amdgcn_mfma_f32_32x32x16_bf16(a2, b2, acc20, 0, 0, 0);
    }
    if (val1t) {
      bf16x8 a1 = *(const bf16x8*)&sDen[BUF][cc2][rowa1][0];
      bf16x8 b1 = *(const bf16x8*)&sGT[BUF][cc2][rowb1][0];
      bf16x8 a2 = *(const bf16x8*)&sG[BUF][cc2][rowa1][0];
      bf16x8 b2 = *(const bf16x8*)&sVT[BUF][cc2][rowb1][0];
      acc11 = __builtin_amdgcn_mfma_f32_32x32x16_bf16(a1, b1, acc11, 0, 0, 0);
      acc21 = __builtin_amdgcn_mfma_f32_32x32x16_bf16(a2, b2, acc21, 0, 0, 0);
    }
  };

  load0(0, vA0); load1(0, vA1);
  load0(1, vB0); load1(1, vB1);
  wr(vA0, vA1, d00, d10);
  __syncthreads();
  for (int p = 0; p < NP; p += 2) {
    if (p + 2 < NP) { load0(p + 2, vA0); load1(p + 2, vA1); }
    mf(0);
    wr(vB0, vB1, d01, d11);
    wg_barrier();
    if (p + 3 < NP) { load0(p + 3, vB0); load1(p + 3, vB1); }
    mf(1);
    if (p + 2 < NP) wr(vA0, vA1, d00, d10);
    wg_barrier();
  }
  float g3 = 0.f;
  #pragma unroll
  for (int r2 = 0; r2 < 16; ++r2) g3 += acc10[r2] * acc20[r2];
  if (val1t) {
    #pragma unroll
    for (int r2 = 0; r2 < 16; ++r2) g3 += acc11[r2] * acc21[r2];
  }
  #pragma unroll
  for (int o = 32; o; o >>= 1) g3 += __shfl_xor(g3, o);
  if (lane == 0) red[wid] = g3;
  __syncthreads();
  if (tid == 0) {
    float s3 = 0.f;
    #pragma unroll
    for (int i = 0; i < 8; ++i) s3 += red[i];
    sp2[bid] = s3;
  }
}

// ---- final reduction of per-block slabs (no atomics anywhere) ----
__global__ __launch_bounds__(512) void finalize_k(
    const float* __restrict__ sp1, const float* __restrict__ sp2,
    float* __restrict__ out) {
  __shared__ float red[8][10];
  int tid = threadIdx.x;
  int wid = tid >> 6, lane = tid & 63;
  float v[10];
  const float* a = sp1 + (size_t)tid * 12;
  #pragma unroll
  for (int i = 0; i < 9; ++i) v[i] = a[i];
  v[9] = sp2[2 * tid] + sp2[2 * tid + 1];
  #pragma unroll
  for (int i = 0; i < 10; ++i) {
    float s = v[i];
    #pragma unroll
    for (int o = 32; o; o >>= 1) s += __shfl_xor(s, o);
    v[i] = s;
  }
  if (lane == 0) {
    #pragma unroll
    for (int i = 0; i < 10; ++i) red[wid][i] = v[i];
  }
  __syncthreads();
  if (tid == 0) {
    float t[10];
    #pragma unroll
    for (int i = 0; i < 10; ++i) {
      float s = 0.f;
      #pragma unroll
      for (int w2 = 0; w2 < 8; ++w2) s += red[w2][i];
      t[i] = s;
    }
    float ce_s = t[0], ce_e = t[1], kls = t[2], kle = t[3];
    float w = t[4], spn = t[5], nans = t[6];
    float gw1 = t[7], gw2 = t[8], gw3 = t[9];
    float l_qa = (ce_s + ce_e) / (2.f * Bn);
    float l_fgw = (ALPHA * (gw1 + gw2 - 2.f * gw3) + (1.f - ALPHA) * w) / Bn;
    float l_span = (nans > 0.f) ? spn / fmaxf(nans, 1.f) : 0.f;
    float l_cons = 2.f * (kls + kle) / Bn;  // T^2 * ((kls+kle)/B) / 2 with T=2
    float total = l_qa + L_FGW * l_fgw + L_SPAN * l_span + L_CONS * l_cons;
    out[0] = total; out[1] = l_qa; out[2] = l_fgw; out[3] = l_span; out[4] = l_cons;
  }
}

extern "C" void kernel_launch(void* const* d_in, const int* in_sizes, int n_in,
                              void* d_out, int out_size, void* d_ws, size_t ws_size,
                              hipStream_t stream) {
  const float* en  = (const float*)d_in[0];
  const float* vi  = (const float*)d_in[1];
  const float* gam = (const float*)d_in[2];
  const float* Den = (const float*)d_in[3];
  const float* Dvi = (const float*)d_in[4];
  const float* M   = (const float*)d_in[5];
  const int* enst  = (const int*)d_in[6];
  const int* enen  = (const int*)d_in[7];
  const float* w_s = (const float*)d_in[8];
  const float* b_s = (const float*)d_in[9];
  const float* w_e = (const float*)d_in[10];
  const float* b_e = (const float*)d_in[11];
  float* ws = (float*)d_ws;
  float* wsl = ws;                         // 4*BK logits
  float* sp1 = ws + (size_t)4 * BK;        // 512*12 stats partials
  float* sp2 = sp1 + 12 * Bn;              // 1024 fgw gw3 partials
  float* out = (float*)d_out;

  qa_logits_k<<<(2 * BK) / 4, 256, 0, stream>>>(en, vi, w_s, b_s, w_e, b_e, wsl);
  stats_k<<<Bn, 512, 0, stream>>>(gam, M, Den, Dvi, enst, enen, wsl, sp1);
  fgw_k<<<2 * Bn, 512, 0, stream>>>(Den, Dvi, gam, sp2);
  finalize_k<<<1, 512, 0, stream>>>(sp1, sp2, out);
}